// Round 3
// baseline (244.081 us; speedup 1.0000x reference)
//
#include <hip/hip_runtime.h>
#include <math.h>

// Problem constants: B=4, H=16, L=4096, D=64, S=128
constexpr int BB = 4;
constexpr int HH = 16;
constexpr int LL = 4096;
constexpr int DD = 64;
constexpr int SS = 128;
constexpr int BM = 128;            // rows per group
constexpr int GG = 2;              // groups per block (256 rows/block)

// R7 post-mortem: kernel ~77us vs 28us HBM floor; all pipes idle ->
// latency-bound one-shot blocks (stage->barrier->6-deep MFMA chain->reduce->
// write, no loop to pipeline). R8: 2 groups/block with A-prefetch across
// groups (loads for g+1 issued before MFMA of g), B staged once per 256 rows,
// MFMA restructured to 2x independent 3-deep chains per (ct,rtb), med3-based
// branch-free top-2 select. __launch_bounds__(256,4) pins 4 blocks/CU.
constexpr float TAU = 2e-3f;

typedef __attribute__((ext_vector_type(8))) short bf16x8;   // 8 bf16 = 4 VGPR
typedef __attribute__((ext_vector_type(4))) float f32x4;

#define MFMA16 __builtin_amdgcn_mfma_f32_16x16x32_bf16

__device__ __forceinline__ unsigned short f2bf(float v) {
    unsigned u = __float_as_uint(v);
    return (unsigned short)((u + 0x7fffu + ((u >> 16) & 1u)) >> 16);  // RNE
}

// split 8 consecutive floats into hi (bf16 trunc) / lo (bf16 RNE of residual)
__device__ __forceinline__ void split8(const float4 va, const float4 vb,
                                       uint4* hi, uint4* lo) {
    const float v[8] = {va.x, va.y, va.z, va.w, vb.x, vb.y, vb.z, vb.w};
    unsigned hw[4], lw[4];
    #pragma unroll
    for (int p = 0; p < 4; ++p) {
        const unsigned u0 = __float_as_uint(v[2 * p]);
        const unsigned u1 = __float_as_uint(v[2 * p + 1]);
        const unsigned h0 = u0 & 0xffff0000u;
        const unsigned h1 = u1 & 0xffff0000u;
        hw[p] = (u0 >> 16) | h1;
        lw[p] = (unsigned)f2bf(v[2 * p] - __uint_as_float(h0))
              | ((unsigned)f2bf(v[2 * p + 1] - __uint_as_float(h1)) << 16);
    }
    *hi = make_uint4(hw[0], hw[1], hw[2], hw[3]);
    *lo = make_uint4(lw[0], lw[1], lw[2], lw[3]);
}

union FragU { uint4 q; bf16x8 v; };

// ---- pre-kernel: c [H,S,D] fp32 -> ws fragment tiles, hi/lo bf16 ----
__global__ __launch_bounds__(256) void convert_c_kernel(
    const float* __restrict__ c, unsigned char* __restrict__ ws)
{
    const int sid = blockIdx.x * 256 + threadIdx.x;  // 0..16383
    const int h  = sid >> 10;
    const int r  = sid & 1023;
    const int kt = r >> 9;
    const int ct = (r >> 6) & 7;
    const int ln = r & 63;
    const int cc = ct * 16 + (ln & 15);
    const int k0 = kt * 32 + (ln >> 4) * 8;
    const float4* src = (const float4*)(c + ((size_t)h * SS + cc) * DD + k0);
    uint4 hi, lo;
    split8(src[0], src[1], &hi, &lo);
    unsigned char* base =
        ws + (size_t)h * 32768 + (size_t)(((kt << 3) | ct) * 1024 + ln * 16);
    *(uint4*)(base) = hi;                 // sp=0 (hi) tiles
    *(uint4*)(base + 16384) = lo;         // sp=1 (lo) tiles at +16KB
}

__device__ __forceinline__ void load_a(const float* __restrict__ x,
                                       long long rbase, int wv, int lane,
                                       float4* raw) {
    const int ln15 = lane & 15;
    const int k0 = (lane >> 4) * 8;
    #pragma unroll
    for (int rtb = 0; rtb < 2; ++rtb) {
        const float* xr =
            x + (size_t)(rbase + wv * 32 + rtb * 16 + ln15) * DD + k0;
        #pragma unroll
        for (int kt = 0; kt < 2; ++kt) {
            raw[rtb * 4 + kt * 2 + 0] = *(const float4*)(xr + kt * 32);
            raw[rtb * 4 + kt * 2 + 1] = *(const float4*)(xr + kt * 32 + 4);
        }
    }
}

__device__ __forceinline__ void split_a(const float4* raw, bf16x8 af[2][2][2]) {
    #pragma unroll
    for (int rtb = 0; rtb < 2; ++rtb)
        #pragma unroll
        for (int kt = 0; kt < 2; ++kt) {
            FragU hi, lo;
            split8(raw[rtb * 4 + kt * 2], raw[rtb * 4 + kt * 2 + 1],
                   &hi.q, &lo.q);
            af[rtb][kt][0] = hi.v;
            af[rtb][kt][1] = lo.v;
        }
}

template <bool USE_WS>
__global__ __launch_bounds__(256, 4) void quantizer_kernel(
    const float* __restrict__ x,               // [B,H,L,D]
    const float* __restrict__ c,               // [H,S,D]
    const unsigned char* __restrict__ ws,      // pre-converted B tiles
    float* __restrict__ out,                   // [B,H,L,S] one-hot
    float* __restrict__ out_c)                 // [H,S,D] copy of c
{
    __shared__ __align__(16) unsigned char smemB[32768];  // B tiles only
    __shared__ int amax[BM];
    __shared__ int s_nflag;
    __shared__ int s_flag[BM];
    __shared__ float s_fsc[SS];

    const int tid = threadIdx.x;
    const int wv = tid >> 6;
    const int lane = tid & 63;
    const int ln15 = lane & 15;
    const int blk = blockIdx.x;
    const long long base0 = (long long)blk * (GG * BM);
    const int h = (int)((base0 >> 12) & (HH - 1));   // 4096 rows per (b,h)
    const float* __restrict__ chead = c + (size_t)h * SS * DD;

    if (tid == 0) s_nflag = 0;

    // ---- stage B tiles into LDS (once per 256 rows) ----
    if (USE_WS) {
        const unsigned char* wsb = ws + (size_t)h * 32768;
        #pragma unroll
        for (int it = 0; it < 8; ++it) {
            const unsigned off = (unsigned)(wv * 8192 + it * 1024);
            __builtin_amdgcn_global_load_lds(
                (const __attribute__((address_space(1))) unsigned*)
                    (wsb + off + (unsigned)(lane * 16)),
                (__attribute__((address_space(3))) unsigned*)(smemB + off),
                16, 0, 0);
        }
    } else {
        #pragma unroll
        for (int it = 0; it < 4; ++it) {
            const int sid = it * 256 + tid;        // 0..1023
            const int kt = sid >> 9;
            const int ct = (sid >> 6) & 7;
            const int ln = sid & 63;
            const int cc = ct * 16 + (ln & 15);
            const int k0 = kt * 32 + (ln >> 4) * 8;
            const float4* src = (const float4*)(chead + (size_t)cc * DD + k0);
            uint4 hi, lo;
            split8(src[0], src[1], &hi, &lo);
            unsigned char* dst = smemB + ((kt << 3) | ct) * 1024 + ln * 16;
            *(uint4*)dst = hi;
            *(uint4*)(dst + 16384) = lo;
        }
    }

    // ---- A for group 0: global -> registers, split in-reg ----
    float4 xraw[8];
    load_a(x, base0, wv, lane, xraw);
    bf16x8 af[2][2][2];   // [rtb][kt][sp]  sp0=hi sp1=lo
    split_a(xraw, af);

    __syncthreads();   // B tiles visible (drains global_load_lds)

    #pragma unroll
    for (int g = 0; g < GG; ++g) {
        const long long rg = base0 + (long long)g * BM;

        // prefetch next group's raw A before compute (covered by MFMA phase)
        if (g + 1 < GG) load_a(x, base0 + (long long)(g + 1) * BM,
                               wv, lane, xraw);

        // ---- MFMA phase: 8 col-tiles, 4 independent 3-deep chains each ----
        float m1[2][4], m2[2][4];
        int   mi_[2][4];
        #pragma unroll
        for (int rtb = 0; rtb < 2; ++rtb)
            #pragma unroll
            for (int r = 0; r < 4; ++r) {
                m1[rtb][r] = -INFINITY; m2[rtb][r] = -INFINITY;
                mi_[rtb][r] = 0;
            }

        #pragma unroll
        for (int ct = 0; ct < 8; ++ct) {
            const unsigned bb = (unsigned)(ct << 10) + (unsigned)(lane * 16);
            const bf16x8 b10 = *(const bf16x8*)(smemB + bb);          // hi kt0
            const bf16x8 b11 = *(const bf16x8*)(smemB + bb + 8192);   // hi kt1
            const bf16x8 b20 = *(const bf16x8*)(smemB + bb + 16384);  // lo kt0
            const bf16x8 b21 = *(const bf16x8*)(smemB + bb + 24576);  // lo kt1
            #pragma unroll
            for (int rtb = 0; rtb < 2; ++rtb) {
                f32x4 a0 = {0.f, 0.f, 0.f, 0.f};
                f32x4 a1 = {0.f, 0.f, 0.f, 0.f};
                a0 = MFMA16(af[rtb][0][1], b10, a0, 0, 0, 0);  // lo*hi kt0
                a0 = MFMA16(af[rtb][0][0], b20, a0, 0, 0, 0);  // hi*lo kt0
                a0 = MFMA16(af[rtb][0][0], b10, a0, 0, 0, 0);  // hi*hi kt0
                a1 = MFMA16(af[rtb][1][1], b11, a1, 0, 0, 0);  // lo*hi kt1
                a1 = MFMA16(af[rtb][1][0], b21, a1, 0, 0, 0);  // hi*lo kt1
                a1 = MFMA16(af[rtb][1][0], b11, a1, 0, 0, 0);  // hi*hi kt1
                #pragma unroll
                for (int r = 0; r < 4; ++r) {
                    const float v = a0[r] + a1[r];
                    const int col = ct * 16 + ln15;
                    // top-2: m2' = med3(m1, v, m2); m1' = max(m1, v)
                    m2[rtb][r] =
                        __builtin_amdgcn_fmed3f(m1[rtb][r], v, m2[rtb][r]);
                    if (v > m1[rtb][r]) { m1[rtb][r] = v; mi_[rtb][r] = col; }
                }
            }
        }

        // ---- per-row top-2 reduce across the 16 lanes sharing each row ----
        #pragma unroll
        for (int rtb = 0; rtb < 2; ++rtb) {
            #pragma unroll
            for (int r = 0; r < 4; ++r) {
                float a1 = m1[rtb][r], a2 = m2[rtb][r];
                int ai = mi_[rtb][r];
                #pragma unroll
                for (int off = 1; off <= 8; off <<= 1) {
                    const float o1 = __shfl_xor(a1, off);
                    const float o2 = __shfl_xor(a2, off);
                    const int   oi = __shfl_xor(ai, off);
                    const bool take = (o1 > a1) || (o1 == a1 && oi < ai);
                    const float n2 = take ? fmaxf(a1, o2) : fmaxf(a2, o1);
                    if (take) { a1 = o1; ai = oi; }
                    a2 = n2;
                }
                if (ln15 == 0) {
                    const int row = (2 * wv + rtb) * 16 + (lane >> 4) * 4 + r;
                    if (a1 - a2 >= TAU) {
                        amax[row] = ai;
                    } else {
                        const int p = atomicAdd(&s_nflag, 1);
                        s_flag[p] = row;
                    }
                }
            }
        }
        __syncthreads();

        // ---- exact fp32 fallback for near-tie rows ----
        const int nf = s_nflag;
        for (int f = 0; f < nf; ++f) {
            const int row = s_flag[f];
            if (tid < SS) {
                const float4* __restrict__ xr =
                    (const float4*)(x + (size_t)(rg + row) * DD);
                const float4* __restrict__ cr =
                    (const float4*)(chead + (size_t)tid * DD);
                float sc = 0.f;
                #pragma unroll
                for (int q = 0; q < 16; ++q) {
                    const float4 a = xr[q];
                    const float4 b = cr[q];
                    sc = fmaf(a.x, b.x, sc); sc = fmaf(a.y, b.y, sc);
                    sc = fmaf(a.z, b.z, sc); sc = fmaf(a.w, b.w, sc);
                }
                s_fsc[tid] = sc;
            }
            __syncthreads();
            if (tid == 0) {
                float bv = s_fsc[0]; int bi = 0;
                for (int s = 1; s < SS; ++s)
                    if (s_fsc[s] > bv) { bv = s_fsc[s]; bi = s; }
                amax[row] = bi;
            }
            __syncthreads();
        }
        if (tid == 0) s_nflag = 0;   // reset for next group (ordered by the
                                     // group-end barrier below)

        // ---- cooperative coalesced one-hot write: 128 rows * 32 float4 ----
        float4* __restrict__ op = (float4*)(out + (size_t)rg * SS);
        #pragma unroll 4
        for (int i = tid; i < BM * (SS / 4); i += 256) {
            const int rr = i >> 5;
            const int s0 = (i & 31) * 4;
            const int am = amax[rr];
            float4 v;
            v.x = (s0 + 0 == am) ? 1.f : 0.f;
            v.y = (s0 + 1 == am) ? 1.f : 0.f;
            v.z = (s0 + 2 == am) ? 1.f : 0.f;
            v.w = (s0 + 3 == am) ? 1.f : 0.f;
            op[i] = v;
        }
        __syncthreads();   // amax/flag safe to reuse; s_nflag reset visible

        // split prefetched raw A into fragments for next group
        if (g + 1 < GG) split_a(xraw, af);
    }

    // ---- copy c to second output region (first 128 blocks) ----
    if (blk < 128) {
        const float4* __restrict__ src = (const float4*)c;
        float4* __restrict__ dst = (float4*)out_c;
        const int idx = blk * 256 + tid;
        dst[idx] = src[idx];
    }
}

extern "C" void kernel_launch(void* const* d_in, const int* in_sizes, int n_in,
                              void* d_out, int out_size, void* d_ws, size_t ws_size,
                              hipStream_t stream) {
    const float* x = (const float*)d_in[0];   // [B,H,L,D] fp32
    const float* c = (const float*)d_in[1];   // [H,S,D]   fp32
    float* out = (float*)d_out;               // onehot [B,H,L,S] then c [H,S,D]
    float* out_c = out + (size_t)BB * HH * LL * SS;

    const int rows = BB * HH * LL;            // 262144
    const int blocks = rows / (GG * BM);      // 1024
    const size_t ws_need = (size_t)HH * 32768; // 512 KB

    if (d_ws != nullptr && ws_size >= ws_need) {
        convert_c_kernel<<<64, 256, 0, stream>>>(c, (unsigned char*)d_ws);
        quantizer_kernel<true><<<blocks, 256, 0, stream>>>(
            x, c, (const unsigned char*)d_ws, out, out_c);
    } else {
        quantizer_kernel<false><<<blocks, 256, 0, stream>>>(
            x, c, nullptr, out, out_c);
    }
}

// Round 4
// 212.591 us; speedup vs baseline: 1.1481x; 1.1481x over previous
//
#include <hip/hip_runtime.h>
#include <math.h>

// Problem constants: B=4, H=16, L=4096, D=64, S=128
constexpr int BB = 4;
constexpr int HH = 16;
constexpr int LL = 4096;
constexpr int DD = 64;
constexpr int SS = 128;
constexpr int BM = 128;            // rows per group
constexpr int GG = 2;              // groups per block (256 rows/block)

// R8 post-mortem: __launch_bounds__(256,4) register cap (VGPR 64) spilled
// ~400B/thread -> +105MB WRITE, +83MB FETCH of scratch traffic, kernel
// 77->107us. R9: same structure, cap lifted to (256,2) (256-VGPR budget, no
// spill), non-temporal one-hot stores (write-once data; stop evicting x from
// L2/L3), out_c copy folded into the convert pre-kernel.
constexpr float TAU = 2e-3f;

typedef __attribute__((ext_vector_type(8))) short bf16x8;   // 8 bf16 = 4 VGPR
typedef __attribute__((ext_vector_type(4))) float f32x4;

#define MFMA16 __builtin_amdgcn_mfma_f32_16x16x32_bf16

__device__ __forceinline__ unsigned short f2bf(float v) {
    unsigned u = __float_as_uint(v);
    return (unsigned short)((u + 0x7fffu + ((u >> 16) & 1u)) >> 16);  // RNE
}

// split 8 consecutive floats into hi (bf16 trunc) / lo (bf16 RNE of residual)
__device__ __forceinline__ void split8(const float4 va, const float4 vb,
                                       uint4* hi, uint4* lo) {
    const float v[8] = {va.x, va.y, va.z, va.w, vb.x, vb.y, vb.z, vb.w};
    unsigned hw[4], lw[4];
    #pragma unroll
    for (int p = 0; p < 4; ++p) {
        const unsigned u0 = __float_as_uint(v[2 * p]);
        const unsigned u1 = __float_as_uint(v[2 * p + 1]);
        const unsigned h0 = u0 & 0xffff0000u;
        const unsigned h1 = u1 & 0xffff0000u;
        hw[p] = (u0 >> 16) | h1;
        lw[p] = (unsigned)f2bf(v[2 * p] - __uint_as_float(h0))
              | ((unsigned)f2bf(v[2 * p + 1] - __uint_as_float(h1)) << 16);
    }
    *hi = make_uint4(hw[0], hw[1], hw[2], hw[3]);
    *lo = make_uint4(lw[0], lw[1], lw[2], lw[3]);
}

union FragU { uint4 q; bf16x8 v; };

// ---- pre-kernel: c [H,S,D] fp32 -> ws fragment tiles (hi/lo bf16),
//      plus the out_c passthrough copy (write-once, non-temporal). ----
__global__ __launch_bounds__(256) void convert_c_kernel(
    const float* __restrict__ c, unsigned char* __restrict__ ws,
    float* __restrict__ out_c)
{
    const int sid = blockIdx.x * 256 + threadIdx.x;  // 0..16383
    const int h  = sid >> 10;
    const int r  = sid & 1023;
    const int kt = r >> 9;
    const int ct = (r >> 6) & 7;
    const int ln = r & 63;
    const int cc = ct * 16 + (ln & 15);
    const int k0 = kt * 32 + (ln >> 4) * 8;
    const float4* src = (const float4*)(c + ((size_t)h * SS + cc) * DD + k0);
    uint4 hi, lo;
    split8(src[0], src[1], &hi, &lo);
    unsigned char* base =
        ws + (size_t)h * 32768 + (size_t)(((kt << 3) | ct) * 1024 + ln * 16);
    *(uint4*)(base) = hi;                 // sp=0 (hi) tiles
    *(uint4*)(base + 16384) = lo;         // sp=1 (lo) tiles at +16KB

    // out_c copy: 32768 float4 total = 2 per thread
    const f32x4* __restrict__ s4 = (const f32x4*)c;
    f32x4* __restrict__ d4 = (f32x4*)out_c;
    __builtin_nontemporal_store(s4[sid], d4 + sid);
    __builtin_nontemporal_store(s4[sid + 16384], d4 + sid + 16384);
}

__device__ __forceinline__ void load_a(const float* __restrict__ x,
                                       long long rbase, int wv, int lane,
                                       float4* raw) {
    const int ln15 = lane & 15;
    const int k0 = (lane >> 4) * 8;
    #pragma unroll
    for (int rtb = 0; rtb < 2; ++rtb) {
        const float* xr =
            x + (size_t)(rbase + wv * 32 + rtb * 16 + ln15) * DD + k0;
        #pragma unroll
        for (int kt = 0; kt < 2; ++kt) {
            raw[rtb * 4 + kt * 2 + 0] = *(const float4*)(xr + kt * 32);
            raw[rtb * 4 + kt * 2 + 1] = *(const float4*)(xr + kt * 32 + 4);
        }
    }
}

__device__ __forceinline__ void split_a(const float4* raw, bf16x8 af[2][2][2]) {
    #pragma unroll
    for (int rtb = 0; rtb < 2; ++rtb)
        #pragma unroll
        for (int kt = 0; kt < 2; ++kt) {
            FragU hi, lo;
            split8(raw[rtb * 4 + kt * 2], raw[rtb * 4 + kt * 2 + 1],
                   &hi.q, &lo.q);
            af[rtb][kt][0] = hi.v;
            af[rtb][kt][1] = lo.v;
        }
}

template <bool USE_WS>
__global__ __launch_bounds__(256, 2) void quantizer_kernel(
    const float* __restrict__ x,               // [B,H,L,D]
    const float* __restrict__ c,               // [H,S,D]
    const unsigned char* __restrict__ ws,      // pre-converted B tiles
    float* __restrict__ out,                   // [B,H,L,S] one-hot
    float* __restrict__ out_c)                 // [H,S,D] copy of c
{
    __shared__ __align__(16) unsigned char smemB[32768];  // B tiles only
    __shared__ int amax[BM];
    __shared__ int s_nflag;
    __shared__ int s_flag[BM];
    __shared__ float s_fsc[SS];

    const int tid = threadIdx.x;
    const int wv = tid >> 6;
    const int lane = tid & 63;
    const int ln15 = lane & 15;
    const int blk = blockIdx.x;
    const long long base0 = (long long)blk * (GG * BM);
    const int h = (int)((base0 >> 12) & (HH - 1));   // 4096 rows per (b,h)
    const float* __restrict__ chead = c + (size_t)h * SS * DD;

    if (tid == 0) s_nflag = 0;

    // ---- stage B tiles into LDS (once per 256 rows) ----
    if (USE_WS) {
        const unsigned char* wsb = ws + (size_t)h * 32768;
        #pragma unroll
        for (int it = 0; it < 8; ++it) {
            const unsigned off = (unsigned)(wv * 8192 + it * 1024);
            __builtin_amdgcn_global_load_lds(
                (const __attribute__((address_space(1))) unsigned*)
                    (wsb + off + (unsigned)(lane * 16)),
                (__attribute__((address_space(3))) unsigned*)(smemB + off),
                16, 0, 0);
        }
    } else {
        #pragma unroll
        for (int it = 0; it < 4; ++it) {
            const int sid = it * 256 + tid;        // 0..1023
            const int kt = sid >> 9;
            const int ct = (sid >> 6) & 7;
            const int ln = sid & 63;
            const int cc = ct * 16 + (ln & 15);
            const int k0 = kt * 32 + (ln >> 4) * 8;
            const float4* src = (const float4*)(chead + (size_t)cc * DD + k0);
            uint4 hi, lo;
            split8(src[0], src[1], &hi, &lo);
            unsigned char* dst = smemB + ((kt << 3) | ct) * 1024 + ln * 16;
            *(uint4*)dst = hi;
            *(uint4*)(dst + 16384) = lo;
        }
    }

    // ---- A for group 0: global -> registers, split in-reg ----
    float4 xraw[8];
    load_a(x, base0, wv, lane, xraw);
    bf16x8 af[2][2][2];   // [rtb][kt][sp]  sp0=hi sp1=lo
    split_a(xraw, af);

    __syncthreads();   // B tiles visible (drains global_load_lds)

    #pragma unroll
    for (int g = 0; g < GG; ++g) {
        const long long rg = base0 + (long long)g * BM;

        // prefetch next group's raw A before compute (covered by MFMA phase)
        if (g + 1 < GG) load_a(x, base0 + (long long)(g + 1) * BM,
                               wv, lane, xraw);

        // ---- MFMA phase: 8 col-tiles, 4 independent 3-deep chains each ----
        float m1[2][4], m2[2][4];
        int   mi_[2][4];
        #pragma unroll
        for (int rtb = 0; rtb < 2; ++rtb)
            #pragma unroll
            for (int r = 0; r < 4; ++r) {
                m1[rtb][r] = -INFINITY; m2[rtb][r] = -INFINITY;
                mi_[rtb][r] = 0;
            }

        #pragma unroll
        for (int ct = 0; ct < 8; ++ct) {
            const unsigned bb = (unsigned)(ct << 10) + (unsigned)(lane * 16);
            const bf16x8 b10 = *(const bf16x8*)(smemB + bb);          // hi kt0
            const bf16x8 b11 = *(const bf16x8*)(smemB + bb + 8192);   // hi kt1
            const bf16x8 b20 = *(const bf16x8*)(smemB + bb + 16384);  // lo kt0
            const bf16x8 b21 = *(const bf16x8*)(smemB + bb + 24576);  // lo kt1
            #pragma unroll
            for (int rtb = 0; rtb < 2; ++rtb) {
                f32x4 a0 = {0.f, 0.f, 0.f, 0.f};
                f32x4 a1 = {0.f, 0.f, 0.f, 0.f};
                a0 = MFMA16(af[rtb][0][1], b10, a0, 0, 0, 0);  // lo*hi kt0
                a0 = MFMA16(af[rtb][0][0], b20, a0, 0, 0, 0);  // hi*lo kt0
                a0 = MFMA16(af[rtb][0][0], b10, a0, 0, 0, 0);  // hi*hi kt0
                a1 = MFMA16(af[rtb][1][1], b11, a1, 0, 0, 0);  // lo*hi kt1
                a1 = MFMA16(af[rtb][1][0], b21, a1, 0, 0, 0);  // hi*lo kt1
                a1 = MFMA16(af[rtb][1][0], b11, a1, 0, 0, 0);  // hi*hi kt1
                #pragma unroll
                for (int r = 0; r < 4; ++r) {
                    const float v = a0[r] + a1[r];
                    const int col = ct * 16 + ln15;
                    // top-2: m2' = med3(m1, v, m2); m1' = max(m1, v)
                    m2[rtb][r] =
                        __builtin_amdgcn_fmed3f(m1[rtb][r], v, m2[rtb][r]);
                    if (v > m1[rtb][r]) { m1[rtb][r] = v; mi_[rtb][r] = col; }
                }
            }
        }

        // ---- per-row top-2 reduce across the 16 lanes sharing each row ----
        #pragma unroll
        for (int rtb = 0; rtb < 2; ++rtb) {
            #pragma unroll
            for (int r = 0; r < 4; ++r) {
                float a1 = m1[rtb][r], a2 = m2[rtb][r];
                int ai = mi_[rtb][r];
                #pragma unroll
                for (int off = 1; off <= 8; off <<= 1) {
                    const float o1 = __shfl_xor(a1, off);
                    const float o2 = __shfl_xor(a2, off);
                    const int   oi = __shfl_xor(ai, off);
                    const bool take = (o1 > a1) || (o1 == a1 && oi < ai);
                    const float n2 = take ? fmaxf(a1, o2) : fmaxf(a2, o1);
                    if (take) { a1 = o1; ai = oi; }
                    a2 = n2;
                }
                if (ln15 == 0) {
                    const int row = (2 * wv + rtb) * 16 + (lane >> 4) * 4 + r;
                    if (a1 - a2 >= TAU) {
                        amax[row] = ai;
                    } else {
                        const int p = atomicAdd(&s_nflag, 1);
                        s_flag[p] = row;
                    }
                }
            }
        }
        __syncthreads();

        // ---- exact fp32 fallback for near-tie rows ----
        const int nf = s_nflag;
        for (int f = 0; f < nf; ++f) {
            const int row = s_flag[f];
            if (tid < SS) {
                const float4* __restrict__ xr =
                    (const float4*)(x + (size_t)(rg + row) * DD);
                const float4* __restrict__ cr =
                    (const float4*)(chead + (size_t)tid * DD);
                float sc = 0.f;
                #pragma unroll
                for (int q = 0; q < 16; ++q) {
                    const float4 a = xr[q];
                    const float4 b = cr[q];
                    sc = fmaf(a.x, b.x, sc); sc = fmaf(a.y, b.y, sc);
                    sc = fmaf(a.z, b.z, sc); sc = fmaf(a.w, b.w, sc);
                }
                s_fsc[tid] = sc;
            }
            __syncthreads();
            if (tid == 0) {
                float bv = s_fsc[0]; int bi = 0;
                for (int s = 1; s < SS; ++s)
                    if (s_fsc[s] > bv) { bv = s_fsc[s]; bi = s; }
                amax[row] = bi;
            }
            __syncthreads();
        }
        if (tid == 0) s_nflag = 0;   // visible to next group after the
                                     // group-end barrier below

        // ---- coalesced one-hot write (non-temporal: write-once data) ----
        f32x4* __restrict__ op = (f32x4*)(out + (size_t)rg * SS);
        #pragma unroll 4
        for (int i = tid; i < BM * (SS / 4); i += 256) {
            const int rr = i >> 5;
            const int s0 = (i & 31) * 4;
            const int am = amax[rr];
            f32x4 v = {(s0 + 0 == am) ? 1.f : 0.f,
                       (s0 + 1 == am) ? 1.f : 0.f,
                       (s0 + 2 == am) ? 1.f : 0.f,
                       (s0 + 3 == am) ? 1.f : 0.f};
            __builtin_nontemporal_store(v, op + i);
        }
        __syncthreads();   // amax/flag safe to reuse; s_nflag reset visible

        // split prefetched raw A into fragments for next group
        if (g + 1 < GG) split_a(xraw, af);
    }

    // ---- copy c to second output region (fallback path only) ----
    if (!USE_WS && blk < 128) {
        const float4* __restrict__ src = (const float4*)c;
        float4* __restrict__ dst = (float4*)out_c;
        const int idx = blk * 256 + tid;
        dst[idx] = src[idx];
    }
}

extern "C" void kernel_launch(void* const* d_in, const int* in_sizes, int n_in,
                              void* d_out, int out_size, void* d_ws, size_t ws_size,
                              hipStream_t stream) {
    const float* x = (const float*)d_in[0];   // [B,H,L,D] fp32
    const float* c = (const float*)d_in[1];   // [H,S,D]   fp32
    float* out = (float*)d_out;               // onehot [B,H,L,S] then c [H,S,D]
    float* out_c = out + (size_t)BB * HH * LL * SS;

    const int rows = BB * HH * LL;            // 262144
    const int blocks = rows / (GG * BM);      // 1024
    const size_t ws_need = (size_t)HH * 32768; // 512 KB

    if (d_ws != nullptr && ws_size >= ws_need) {
        convert_c_kernel<<<64, 256, 0, stream>>>(c, (unsigned char*)d_ws,
                                                 out_c);
        quantizer_kernel<true><<<blocks, 256, 0, stream>>>(
            x, c, (const unsigned char*)d_ws, out, out_c);
    } else {
        quantizer_kernel<false><<<blocks, 256, 0, stream>>>(
            x, c, nullptr, out, out_c);
    }
}

// Round 5
// 202.108 us; speedup vs baseline: 1.2077x; 1.0519x over previous
//
#include <hip/hip_runtime.h>
#include <math.h>

// Problem constants: B=4, H=16, L=4096, D=64, S=128
constexpr int BB = 4;
constexpr int HH = 16;
constexpr int LL = 4096;
constexpr int DD = 64;
constexpr int SS = 128;
constexpr int BM = 128;            // rows per group
constexpr int GG = 2;              // groups per block (256 rows/block)

// R9 post-mortem: spill gone (WRITE back to 131MB) but flat at ~84us; VALU
// 20% / MFMA 6% / HBM 26% / occ 15% -> blocks stall on SERIAL phases:
// (a) block-wide fallback: 2 barriers + tid0-serial 128-iter LDS scan
//     (~120cyc/read) per flagged row, all 8 waves waiting;
// (b) group-end __syncthreads drains vmcnt(0) right after 16 NT stores.
// R10: wave-local barrier-free fallback (per-wave LDS list, owning wave
// recomputes 64 lanes x 2 codes sequential-fp32, 6-step shfl argmax);
// amax ping-pong kills the group-end barrier entirely.
constexpr float TAU = 2e-3f;

typedef __attribute__((ext_vector_type(8))) short bf16x8;   // 8 bf16 = 4 VGPR
typedef __attribute__((ext_vector_type(4))) float f32x4;

#define MFMA16 __builtin_amdgcn_mfma_f32_16x16x32_bf16

__device__ __forceinline__ unsigned short f2bf(float v) {
    unsigned u = __float_as_uint(v);
    return (unsigned short)((u + 0x7fffu + ((u >> 16) & 1u)) >> 16);  // RNE
}

// split 8 consecutive floats into hi (bf16 trunc) / lo (bf16 RNE of residual)
__device__ __forceinline__ void split8(const float4 va, const float4 vb,
                                       uint4* hi, uint4* lo) {
    const float v[8] = {va.x, va.y, va.z, va.w, vb.x, vb.y, vb.z, vb.w};
    unsigned hw[4], lw[4];
    #pragma unroll
    for (int p = 0; p < 4; ++p) {
        const unsigned u0 = __float_as_uint(v[2 * p]);
        const unsigned u1 = __float_as_uint(v[2 * p + 1]);
        const unsigned h0 = u0 & 0xffff0000u;
        const unsigned h1 = u1 & 0xffff0000u;
        hw[p] = (u0 >> 16) | h1;
        lw[p] = (unsigned)f2bf(v[2 * p] - __uint_as_float(h0))
              | ((unsigned)f2bf(v[2 * p + 1] - __uint_as_float(h1)) << 16);
    }
    *hi = make_uint4(hw[0], hw[1], hw[2], hw[3]);
    *lo = make_uint4(lw[0], lw[1], lw[2], lw[3]);
}

union FragU { uint4 q; bf16x8 v; };

// ---- pre-kernel: c [H,S,D] fp32 -> ws fragment tiles (hi/lo bf16),
//      plus the out_c passthrough copy (write-once, non-temporal). ----
__global__ __launch_bounds__(256) void convert_c_kernel(
    const float* __restrict__ c, unsigned char* __restrict__ ws,
    float* __restrict__ out_c)
{
    const int sid = blockIdx.x * 256 + threadIdx.x;  // 0..16383
    const int h  = sid >> 10;
    const int r  = sid & 1023;
    const int kt = r >> 9;
    const int ct = (r >> 6) & 7;
    const int ln = r & 63;
    const int cc = ct * 16 + (ln & 15);
    const int k0 = kt * 32 + (ln >> 4) * 8;
    const float4* src = (const float4*)(c + ((size_t)h * SS + cc) * DD + k0);
    uint4 hi, lo;
    split8(src[0], src[1], &hi, &lo);
    unsigned char* base =
        ws + (size_t)h * 32768 + (size_t)(((kt << 3) | ct) * 1024 + ln * 16);
    *(uint4*)(base) = hi;                 // sp=0 (hi) tiles
    *(uint4*)(base + 16384) = lo;         // sp=1 (lo) tiles at +16KB

    // out_c copy: 32768 float4 total = 2 per thread
    const f32x4* __restrict__ s4 = (const f32x4*)c;
    f32x4* __restrict__ d4 = (f32x4*)out_c;
    __builtin_nontemporal_store(s4[sid], d4 + sid);
    __builtin_nontemporal_store(s4[sid + 16384], d4 + sid + 16384);
}

__device__ __forceinline__ void load_a(const float* __restrict__ x,
                                       long long rbase, int wv, int lane,
                                       float4* raw) {
    const int ln15 = lane & 15;
    const int k0 = (lane >> 4) * 8;
    #pragma unroll
    for (int rtb = 0; rtb < 2; ++rtb) {
        const float* xr =
            x + (size_t)(rbase + wv * 32 + rtb * 16 + ln15) * DD + k0;
        #pragma unroll
        for (int kt = 0; kt < 2; ++kt) {
            raw[rtb * 4 + kt * 2 + 0] = *(const float4*)(xr + kt * 32);
            raw[rtb * 4 + kt * 2 + 1] = *(const float4*)(xr + kt * 32 + 4);
        }
    }
}

__device__ __forceinline__ void split_a(const float4* raw, bf16x8 af[2][2][2]) {
    #pragma unroll
    for (int rtb = 0; rtb < 2; ++rtb)
        #pragma unroll
        for (int kt = 0; kt < 2; ++kt) {
            FragU hi, lo;
            split8(raw[rtb * 4 + kt * 2], raw[rtb * 4 + kt * 2 + 1],
                   &hi.q, &lo.q);
            af[rtb][kt][0] = hi.v;
            af[rtb][kt][1] = lo.v;
        }
}

template <bool USE_WS>
__global__ __launch_bounds__(256, 2) void quantizer_kernel(
    const float* __restrict__ x,               // [B,H,L,D]
    const float* __restrict__ c,               // [H,S,D]
    const unsigned char* __restrict__ ws,      // pre-converted B tiles
    float* __restrict__ out,                   // [B,H,L,S] one-hot
    float* __restrict__ out_c)                 // [H,S,D] copy of c
{
    __shared__ __align__(16) unsigned char smemB[32768];  // B tiles only
    __shared__ int amax[GG][BM];               // ping-pong across groups
    __shared__ int s_wcnt[4];                  // per-wave flagged-row count
    __shared__ int s_wlist[4][32];             // per-wave flagged rows

    const int tid = threadIdx.x;
    const int wv = tid >> 6;
    const int lane = tid & 63;
    const int ln15 = lane & 15;
    const int blk = blockIdx.x;
    const long long base0 = (long long)blk * (GG * BM);
    const int h = (int)((base0 >> 12) & (HH - 1));   // 4096 rows per (b,h)
    const float* __restrict__ chead = c + (size_t)h * SS * DD;

    // ---- stage B tiles into LDS (once per 256 rows) ----
    if (USE_WS) {
        const unsigned char* wsb = ws + (size_t)h * 32768;
        #pragma unroll
        for (int it = 0; it < 8; ++it) {
            const unsigned off = (unsigned)(wv * 8192 + it * 1024);
            __builtin_amdgcn_global_load_lds(
                (const __attribute__((address_space(1))) unsigned*)
                    (wsb + off + (unsigned)(lane * 16)),
                (__attribute__((address_space(3))) unsigned*)(smemB + off),
                16, 0, 0);
        }
    } else {
        #pragma unroll
        for (int it = 0; it < 4; ++it) {
            const int sid = it * 256 + tid;        // 0..1023
            const int kt = sid >> 9;
            const int ct = (sid >> 6) & 7;
            const int ln = sid & 63;
            const int cc = ct * 16 + (ln & 15);
            const int k0 = kt * 32 + (ln >> 4) * 8;
            const float4* src = (const float4*)(chead + (size_t)cc * DD + k0);
            uint4 hi, lo;
            split8(src[0], src[1], &hi, &lo);
            unsigned char* dst = smemB + ((kt << 3) | ct) * 1024 + ln * 16;
            *(uint4*)dst = hi;
            *(uint4*)(dst + 16384) = lo;
        }
    }

    // ---- A for group 0: global -> registers, split in-reg ----
    float4 xraw[8];
    load_a(x, base0, wv, lane, xraw);
    bf16x8 af[2][2][2];   // [rtb][kt][sp]  sp0=hi sp1=lo
    split_a(xraw, af);

    __syncthreads();   // B tiles visible (drains global_load_lds)

    #pragma unroll
    for (int g = 0; g < GG; ++g) {
        const long long rg = base0 + (long long)g * BM;
        int* __restrict__ amaxg = amax[g];

        // wave-private flag counter reset (no cross-wave access -> no barrier)
        if (lane == 0) s_wcnt[wv] = 0;

        // prefetch next group's raw A before compute (covered by MFMA phase)
        if (g + 1 < GG) load_a(x, base0 + (long long)(g + 1) * BM,
                               wv, lane, xraw);

        // ---- MFMA phase: 8 col-tiles, 4 independent 3-deep chains each ----
        float m1[2][4], m2[2][4];
        int   mi_[2][4];
        #pragma unroll
        for (int rtb = 0; rtb < 2; ++rtb)
            #pragma unroll
            for (int r = 0; r < 4; ++r) {
                m1[rtb][r] = -INFINITY; m2[rtb][r] = -INFINITY;
                mi_[rtb][r] = 0;
            }

        #pragma unroll
        for (int ct = 0; ct < 8; ++ct) {
            const unsigned bb = (unsigned)(ct << 10) + (unsigned)(lane * 16);
            const bf16x8 b10 = *(const bf16x8*)(smemB + bb);          // hi kt0
            const bf16x8 b11 = *(const bf16x8*)(smemB + bb + 8192);   // hi kt1
            const bf16x8 b20 = *(const bf16x8*)(smemB + bb + 16384);  // lo kt0
            const bf16x8 b21 = *(const bf16x8*)(smemB + bb + 24576);  // lo kt1
            #pragma unroll
            for (int rtb = 0; rtb < 2; ++rtb) {
                f32x4 a0 = {0.f, 0.f, 0.f, 0.f};
                f32x4 a1 = {0.f, 0.f, 0.f, 0.f};
                a0 = MFMA16(af[rtb][0][1], b10, a0, 0, 0, 0);  // lo*hi kt0
                a0 = MFMA16(af[rtb][0][0], b20, a0, 0, 0, 0);  // hi*lo kt0
                a0 = MFMA16(af[rtb][0][0], b10, a0, 0, 0, 0);  // hi*hi kt0
                a1 = MFMA16(af[rtb][1][1], b11, a1, 0, 0, 0);  // lo*hi kt1
                a1 = MFMA16(af[rtb][1][0], b21, a1, 0, 0, 0);  // hi*lo kt1
                a1 = MFMA16(af[rtb][1][0], b11, a1, 0, 0, 0);  // hi*hi kt1
                #pragma unroll
                for (int r = 0; r < 4; ++r) {
                    const float v = a0[r] + a1[r];
                    const int col = ct * 16 + ln15;
                    // top-2: m2' = med3(m1, v, m2); m1' = max(m1, v)
                    m2[rtb][r] =
                        __builtin_amdgcn_fmed3f(m1[rtb][r], v, m2[rtb][r]);
                    if (v > m1[rtb][r]) { m1[rtb][r] = v; mi_[rtb][r] = col; }
                }
            }
        }

        // ---- per-row top-2 reduce across the 16 lanes sharing each row;
        //      leaders either commit amax or push onto the wave list ----
        #pragma unroll
        for (int rtb = 0; rtb < 2; ++rtb) {
            #pragma unroll
            for (int r = 0; r < 4; ++r) {
                float a1 = m1[rtb][r], a2 = m2[rtb][r];
                int ai = mi_[rtb][r];
                #pragma unroll
                for (int off = 1; off <= 8; off <<= 1) {
                    const float o1 = __shfl_xor(a1, off);
                    const float o2 = __shfl_xor(a2, off);
                    const int   oi = __shfl_xor(ai, off);
                    const bool take = (o1 > a1) || (o1 == a1 && oi < ai);
                    const float n2 = take ? fmaxf(a1, o2) : fmaxf(a2, o1);
                    if (take) { a1 = o1; ai = oi; }
                    a2 = n2;
                }
                if (ln15 == 0) {
                    const int row = (2 * wv + rtb) * 16 + (lane >> 4) * 4 + r;
                    if (a1 - a2 >= TAU) {
                        amaxg[row] = ai;
                    } else {
                        const int p = atomicAdd(&s_wcnt[wv], 1);
                        s_wlist[wv][p] = row;
                    }
                }
            }
        }

        // ---- wave-local exact fp32 fallback (no barriers): owning wave
        //      recomputes all 128 scores, 2 codes/lane, sequential-k fmaf
        //      (identical numerics to the all-fp32 kernel that matched ref) --
        const int cnt = s_wcnt[wv];
        for (int f = 0; f < cnt; ++f) {
            const int row = s_wlist[wv][f];
            const float4* __restrict__ xr =
                (const float4*)(x + (size_t)(rg + row) * DD);
            const float4* __restrict__ c0 =
                (const float4*)(chead + (size_t)lane * DD);
            const float4* __restrict__ c1 =
                (const float4*)(chead + (size_t)(lane + 64) * DD);
            float s0 = 0.f, s1 = 0.f;
            #pragma unroll
            for (int q = 0; q < 16; ++q) {
                const float4 a = xr[q];
                const float4 b0 = c0[q];
                const float4 b1 = c1[q];
                s0 = fmaf(a.x, b0.x, s0); s0 = fmaf(a.y, b0.y, s0);
                s0 = fmaf(a.z, b0.z, s0); s0 = fmaf(a.w, b0.w, s0);
                s1 = fmaf(a.x, b1.x, s1); s1 = fmaf(a.y, b1.y, s1);
                s1 = fmaf(a.z, b1.z, s1); s1 = fmaf(a.w, b1.w, s1);
            }
            float v = s0; int bi = lane;
            if (s1 > v) { v = s1; bi = lane + 64; }   // strict >: lower idx wins
            #pragma unroll
            for (int off = 1; off < 64; off <<= 1) {
                const float ov = __shfl_xor(v, off);
                const int   oi = __shfl_xor(bi, off);
                if (ov > v || (ov == v && oi < bi)) { v = ov; bi = oi; }
            }
            if (lane == 0) amaxg[row] = bi;
        }
        __syncthreads();   // all amax[g] writes visible to all waves

        // ---- coalesced one-hot write (non-temporal, fire-and-forget;
        //      no barrier after -> store ack never on the critical path) ----
        f32x4* __restrict__ op = (f32x4*)(out + (size_t)rg * SS);
        #pragma unroll 4
        for (int i = tid; i < BM * (SS / 4); i += 256) {
            const int rr = i >> 5;
            const int s0 = (i & 31) * 4;
            const int am = amaxg[rr];
            f32x4 v = {(s0 + 0 == am) ? 1.f : 0.f,
                       (s0 + 1 == am) ? 1.f : 0.f,
                       (s0 + 2 == am) ? 1.f : 0.f,
                       (s0 + 3 == am) ? 1.f : 0.f};
            __builtin_nontemporal_store(v, op + i);
        }

        // split prefetched raw A into fragments for next group (registers
        // only; next group writes amax[g+1] -> no barrier needed here)
        if (g + 1 < GG) split_a(xraw, af);
    }

    // ---- copy c to second output region (fallback path only) ----
    if (!USE_WS && blk < 128) {
        const float4* __restrict__ src = (const float4*)c;
        float4* __restrict__ dst = (float4*)out_c;
        const int idx = blk * 256 + tid;
        dst[idx] = src[idx];
    }
}

extern "C" void kernel_launch(void* const* d_in, const int* in_sizes, int n_in,
                              void* d_out, int out_size, void* d_ws, size_t ws_size,
                              hipStream_t stream) {
    const float* x = (const float*)d_in[0];   // [B,H,L,D] fp32
    const float* c = (const float*)d_in[1];   // [H,S,D]   fp32
    float* out = (float*)d_out;               // onehot [B,H,L,S] then c [H,S,D]
    float* out_c = out + (size_t)BB * HH * LL * SS;

    const int rows = BB * HH * LL;            // 262144
    const int blocks = rows / (GG * BM);      // 1024
    const size_t ws_need = (size_t)HH * 32768; // 512 KB

    if (d_ws != nullptr && ws_size >= ws_need) {
        convert_c_kernel<<<64, 256, 0, stream>>>(c, (unsigned char*)d_ws,
                                                 out_c);
        quantizer_kernel<true><<<blocks, 256, 0, stream>>>(
            x, c, (const unsigned char*)d_ws, out, out_c);
    } else {
        quantizer_kernel<false><<<blocks, 256, 0, stream>>>(
            x, c, nullptr, out, out_c);
    }
}